// Round 4
// baseline (209.200 us; speedup 1.0000x reference)
//
#include <hip/hip_runtime.h>
#include <stdint.h>

typedef unsigned int uint;
typedef unsigned long long u64;

#define BLK   128
#define NSTEP 9
#define PADF  1e30f
#define SENTV (1 << 30)
#define VOCAB 128000

// Bitonic sort 32 ints ascending.
__device__ __forceinline__ void bsort32i(int (&a)[32]) {
#pragma unroll
    for (int k = 2; k <= 32; k <<= 1) {
#pragma unroll
        for (int j = k >> 1; j > 0; j >>= 1) {
#pragma unroll
            for (int x = 0; x < 32; ++x) {
                int l = x ^ j;
                if (l > x) {
                    int va = a[x], vb = a[l];
                    bool sw = va > vb;
                    int mn = sw ? vb : va;
                    int mx = sw ? va : vb;
                    bool up = (x & k) == 0;
                    a[x] = up ? mn : mx;
                    a[l] = up ? mx : mn;
                }
            }
        }
    }
}

// Bitonic sort 64 u64 keys ascending.
__device__ __forceinline__ void bsort64u(u64 (&a)[64]) {
#pragma unroll
    for (int k = 2; k <= 64; k <<= 1) {
#pragma unroll
        for (int j = k >> 1; j > 0; j >>= 1) {
#pragma unroll
            for (int x = 0; x < 64; ++x) {
                int l = x ^ j;
                if (l > x) {
                    u64 va = a[x], vb = a[l];
                    bool sw = va > vb;
                    u64 mn = sw ? vb : va;
                    u64 mx = sw ? va : vb;
                    bool up = (x & k) == 0;
                    a[x] = up ? mn : mx;
                    a[l] = up ? mx : mn;
                }
            }
        }
    }
}

__global__ __launch_bounds__(BLK, 2)
void beam_kernel(const float* __restrict__ y, const float* __restrict__ h,
                 float* __restrict__ out, int T)
{
#pragma clang fp contract(off)
    // Per-thread column: paths[n*BLK + tid] = packed 2-bit symbols of beam n.
    __shared__ uint paths[32 * BLK];   // 16 KB

    const int tid = threadIdx.x;
    const int tok = blockIdx.x * BLK + tid;
    if (tok >= T) return;

    // ---- ZF equalize + per-position top-2-of-4 QPSK distances (strict fp32) ----
    const float hr = h[2 * tok], hi = h[2 * tok + 1];
    const float den = hr * hr + hi * hi;

    float d0r[NSTEP], d1r[NSTEP];
    uint64_t sympack = 0;                          // 4 bits per step: s0 | s1<<2
    const float C = 0.70710678118654752440f;       // fp32: 0x3F3504F3 == np constellation
#pragma unroll
    for (int l = 0; l < NSTEP; ++l) {
        float yr = y[tok * 18 + l];
        float yi = y[tok * 18 + 9 + l];
        float nr = yr * hr + yi * hi;
        float ni = yi * hr - yr * hi;
        float rr = nr / den;                       // IEEE div
        float ri = ni / den;
        float em = rr - C, ep = rr + C;
        float fm = ri - C, fq = ri + C;
        float aa = em * em, bb = ep * ep, pp = fm * fm, qq = fq * fq;
        // points: idx0=(+,+) idx1=(-,+) idx2=(+,-) idx3=(-,-)
        float q0 = aa + pp;
        float q1 = bb + pp;
        float q2 = aa + qq;
        float q3 = bb + qq;
        // top-2 smallest, ties -> lower index
        float m0 = q0; int s0 = 0;
        if (q1 < m0) { m0 = q1; s0 = 1; }
        if (q2 < m0) { m0 = q2; s0 = 2; }
        if (q3 < m0) { m0 = q3; s0 = 3; }
        float m1 = __builtin_inff(); int s1 = 0;
        if (s0 != 0 && q0 < m1) { m1 = q0; s1 = 0; }
        if (s0 != 1 && q1 < m1) { m1 = q1; s1 = 1; }
        if (s0 != 2 && q2 < m1) { m1 = q2; s1 = 2; }
        if (s0 != 3 && q3 < m1) { m1 = q3; s1 = 3; }
        d0r[l] = m0; d1r[l] = m1;
        sympack |= (uint64_t)(uint)(s0 | (s1 << 2)) << (4 * l);
    }

    // ---- init beams ----
    float S[32];
    S[0] = 0.0f;
#pragma unroll
    for (int n = 1; n < 32; ++n) S[n] = PADF;
#pragma unroll
    for (int n = 0; n < 32; ++n) paths[n * BLK + tid] = 0u;

    // ---- 9 beam steps: top_k emulation via 64-key sort, ANTI-STABLE ties ----
    // key = (fp32 bits << 6) | (63 - flat): equal scores resolve to HIGHER flat
    // index first (emulating numpy introsort's tie behavior at flip events).
    // Scores >= +0.0 so bit patterns are order-monotone. PAD-region reordering
    // is output-invariant (PAD beams always emit -1 / PAD score).
    uint np_[32];
#pragma unroll 1
    for (int t = 0; t < NSTEP; ++t) {
        const float cd0 = d0r[0], cd1 = d1r[0];
#pragma unroll
        for (int kk = 0; kk < NSTEP - 1; ++kk) { d0r[kk] = d0r[kk + 1]; d1r[kk] = d1r[kk + 1]; }
        const uint nib = (uint)sympack & 15u;
        sympack >>= 4;
        const uint s0c = nib & 3u, s1c = nib >> 2;

        u64 K[64];
#pragma unroll
        for (int n = 0; n < 32; ++n) {
            float v0 = S[n] + cd0;
            float v1 = S[n] + cd1;
            K[2 * n]     = ((u64)__float_as_uint(v0) << 6) | (uint)(63 - 2 * n);
            K[2 * n + 1] = ((u64)__float_as_uint(v1) << 6) | (uint)(63 - (2 * n + 1));
        }
        bsort64u(K);

        // winners = K[0..31]; gather parent paths (all reads before any write)
#pragma unroll
        for (int m = 0; m < 32; ++m) {
            uint flat = 63u - ((uint)K[m] & 63u);
            uint par  = flat >> 1;
            uint sym  = (flat & 1u) ? s1c : s0c;
            uint pth  = paths[par * BLK + tid];
            np_[m] = (pth << 2) | sym;
            S[m]   = __uint_as_float((uint)(K[m] >> 6));
        }
#pragma unroll
        for (int m = 0; m < 32; ++m) paths[m * BLK + tid] = np_[m];
    }

    // ---- epilogue: ids, validity, sort, dedup, sort, write ----
    int e[32];
#pragma unroll
    for (int n = 0; n < 32; ++n) {
        int id = (int)(np_[n] >> 1);               // == sum((sym>>rsh)<<lsh)
        bool valid = (S[n] < 5e29f) && (id < VOCAB);
        e[n] = valid ? id : SENTV;
    }
    bsort32i(e);
    int f[32];
    f[0] = e[0];
#pragma unroll
    for (int n = 1; n < 32; ++n) f[n] = (e[n] == e[n - 1]) ? SENTV : e[n];
    bsort32i(f);

    float* out_ids = out + (size_t)tok * 32;
    float* out_sc  = out + (size_t)T * 32 + (size_t)tok * 32;
#pragma unroll
    for (int g = 0; g < 8; ++g) {
        float4 vi;
        vi.x = (f[4 * g + 0] == SENTV) ? -1.0f : (float)f[4 * g + 0];
        vi.y = (f[4 * g + 1] == SENTV) ? -1.0f : (float)f[4 * g + 1];
        vi.z = (f[4 * g + 2] == SENTV) ? -1.0f : (float)f[4 * g + 2];
        vi.w = (f[4 * g + 3] == SENTV) ? -1.0f : (float)f[4 * g + 3];
        *(float4*)(out_ids + 4 * g) = vi;
        float4 vs = make_float4(S[4 * g], S[4 * g + 1], S[4 * g + 2], S[4 * g + 3]);
        *(float4*)(out_sc + 4 * g) = vs;
    }
}

extern "C" void kernel_launch(void* const* d_in, const int* in_sizes, int n_in,
                              void* d_out, int out_size, void* d_ws, size_t ws_size,
                              hipStream_t stream) {
    const float* y = (const float*)d_in[0];
    const float* h = (const float*)d_in[1];
    const int T = in_sizes[0] / 18;               // 131072
    const int grid = (T + BLK - 1) / BLK;         // 1024 blocks of 128
    beam_kernel<<<grid, BLK, 0, stream>>>(y, h, (float*)d_out, T);
}

// Round 5
// 156.385 us; speedup vs baseline: 1.3377x; 1.3377x over previous
//
#include <hip/hip_runtime.h>
#include <stdint.h>

typedef unsigned int uint;
typedef unsigned long long u64;

#define BLK   256
#define VOCAB 128000
#define SENTV (1 << 30)

// Bitonic sort N u64 keys ascending — assumption-free total-order sort.
template<int N>
__device__ __forceinline__ void bsortU(u64 (&a)[N]) {
#pragma unroll
    for (int k = 2; k <= N; k <<= 1) {
#pragma unroll
        for (int j = k >> 1; j > 0; j >>= 1) {
#pragma unroll
            for (int x = 0; x < N; ++x) {
                int l = x ^ j;
                if (l > x) {
                    u64 va = a[x], vb = a[l];
                    bool sw = va > vb;
                    u64 mn = sw ? vb : va, mx = sw ? va : vb;
                    bool up = (x & k) == 0;
                    a[x] = up ? mn : mx;
                    a[l] = up ? mx : mn;
                }
            }
        }
    }
}

// Bitonic sort 32 ints ascending.
__device__ __forceinline__ void bsort32i(int (&a)[32]) {
#pragma unroll
    for (int k = 2; k <= 32; k <<= 1) {
#pragma unroll
        for (int j = k >> 1; j > 0; j >>= 1) {
#pragma unroll
            for (int x = 0; x < 32; ++x) {
                int l = x ^ j;
                if (l > x) {
                    int va = a[x], vb = a[l];
                    bool sw = va > vb;
                    int mn = sw ? vb : va, mx = sw ? va : vb;
                    bool up = (x & k) == 0;
                    a[x] = up ? mn : mx;
                    a[l] = up ? mx : mn;
                }
            }
        }
    }
}

// Build 2R interleaved candidate keys from R real beams.
// key = [score_bits:31]<<24 | (63-flat)<<18 | path18   (path carries below the
// tie-break field; flat unique => total order identical to round-4 semantics).
template<int R>
__device__ __forceinline__ void build_il(const u64 (&K)[32], float cd0, float cd1,
                                         uint s0c, uint s1c, u64 (&C)[2 * R]) {
#pragma clang fp contract(off)
#pragma unroll
    for (int n = 0; n < R; ++n) {
        u64 base = K[n];
        float Sp = __uint_as_float((uint)(base >> 24));
        uint pp = ((uint)base & 0x3FFFFu) << 2;     // parent path, shifted (<=18b)
        float v0 = Sp + cd0, v1 = Sp + cd1;
        C[2 * n]     = ((u64)__float_as_uint(v0) << 24) | ((u64)(uint)(63 - 2 * n) << 18) | (pp | s0c);
        C[2 * n + 1] = ((u64)__float_as_uint(v1) << 24) | ((u64)(uint)(62 - 2 * n) << 18) | (pp | s1c);
    }
}

__global__ __launch_bounds__(BLK, 2)
void beam_kernel(const float* __restrict__ y, const float* __restrict__ h,
                 float* __restrict__ out, int T)
{
#pragma clang fp contract(off)
    const int tok = blockIdx.x * BLK + threadIdx.x;
    if (tok >= T) return;

    // ---- ZF equalize + per-position top-2-of-4 QPSK distances (strict fp32) ----
    const float hr = h[2 * tok], hi = h[2 * tok + 1];
    const float den = hr * hr + hi * hi;

    float d0r[9], d1r[9];
    uint64_t sympack = 0;                          // 4 bits per step: s0 | s1<<2
    const float C = 0.70710678118654752440f;       // fp32 0x3F3504F3 == np constellation
#pragma unroll
    for (int l = 0; l < 9; ++l) {
        float yr = y[tok * 18 + l];
        float yi = y[tok * 18 + 9 + l];
        float nr = yr * hr + yi * hi;
        float ni = yi * hr - yr * hi;
        float rr = nr / den;
        float ri = ni / den;
        float em = rr - C, ep = rr + C;
        float fm = ri - C, fq = ri + C;
        float aa = em * em, bb = ep * ep, pq = fm * fm, qq = fq * fq;
        float q0 = aa + pq, q1 = bb + pq, q2 = aa + qq, q3 = bb + qq;
        float m0 = q0; int s0 = 0;
        if (q1 < m0) { m0 = q1; s0 = 1; }
        if (q2 < m0) { m0 = q2; s0 = 2; }
        if (q3 < m0) { m0 = q3; s0 = 3; }
        float m1 = __builtin_inff(); int s1 = 0;
        if (s0 != 0 && q0 < m1) { m1 = q0; s1 = 0; }
        if (s0 != 1 && q1 < m1) { m1 = q1; s1 = 1; }
        if (s0 != 2 && q2 < m1) { m1 = q2; s1 = 2; }
        if (s0 != 3 && q3 < m1) { m1 = q3; s1 = 3; }
        d0r[l] = m0; d1r[l] = m1;
        sympack |= (uint64_t)(uint)(s0 | (s1 << 2)) << (4 * l);
    }

    // ---- beam state: real beams only (pads are provably output-invariant) ----
    u64 K[32];
#pragma unroll
    for (int n = 0; n < 32; ++n) K[n] = 0;         // K[0]: score=0, path=empty

#define NIB(t) ((uint)(sympack >> (4 * (t))))
    // phases t=0..4: 2,4,8,16,32 real candidates — all survive, sort for order
    { u64 Cc[2];  build_il<1>(K, d0r[0], d1r[0], NIB(0) & 3u, (NIB(0) >> 2) & 3u, Cc);
      bsortU<2>(Cc);
#pragma unroll
      for (int n = 0; n < 2;  ++n) K[n] = Cc[n]; }
    { u64 Cc[4];  build_il<2>(K, d0r[1], d1r[1], NIB(1) & 3u, (NIB(1) >> 2) & 3u, Cc);
      bsortU<4>(Cc);
#pragma unroll
      for (int n = 0; n < 4;  ++n) K[n] = Cc[n]; }
    { u64 Cc[8];  build_il<4>(K, d0r[2], d1r[2], NIB(2) & 3u, (NIB(2) >> 2) & 3u, Cc);
      bsortU<8>(Cc);
#pragma unroll
      for (int n = 0; n < 8;  ++n) K[n] = Cc[n]; }
    { u64 Cc[16]; build_il<8>(K, d0r[3], d1r[3], NIB(3) & 3u, (NIB(3) >> 2) & 3u, Cc);
      bsortU<16>(Cc);
#pragma unroll
      for (int n = 0; n < 16; ++n) K[n] = Cc[n]; }
    { u64 Cc[32]; build_il<16>(K, d0r[4], d1r[4], NIB(4) & 3u, (NIB(4) >> 2) & 3u, Cc);
      bsortU<32>(Cc);
#pragma unroll
      for (int n = 0; n < 32; ++n) K[n] = Cc[n]; }
#undef NIB

    // phases t=5..8: 64 candidates -> sorted top-32.
    // Sort each list fully (no sortedness assumptions => exact tie handling),
    // then bitonic half-cleaner + merge extracts the sorted lowest 32.
    float e0[4] = { d0r[5], d0r[6], d0r[7], d0r[8] };
    float e1[4] = { d1r[5], d1r[6], d1r[7], d1r[8] };
    uint sp = (uint)(sympack >> 20);
#pragma unroll 1
    for (int t = 0; t < 4; ++t) {
        const float cd0 = e0[0], cd1 = e1[0];
#pragma unroll
        for (int k = 0; k < 3; ++k) { e0[k] = e0[k + 1]; e1[k] = e1[k + 1]; }
        const uint nib = sp & 15u; sp >>= 4;
        const uint s0c = nib & 3u, s1c = nib >> 2;

        u64 CA[32], CB[32];
#pragma unroll
        for (int n = 0; n < 32; ++n) {
            u64 base = K[n];
            float Sp = __uint_as_float((uint)(base >> 24));
            uint pp = ((uint)base & 0x3FFFFu) << 2;
            float v0 = Sp + cd0, v1 = Sp + cd1;
            CA[n] = ((u64)__float_as_uint(v0) << 24) | ((u64)(uint)(63 - 2 * n) << 18) | (pp | s0c);
            CB[n] = ((u64)__float_as_uint(v1) << 24) | ((u64)(uint)(62 - 2 * n) << 18) | (pp | s1c);
        }
        bsortU<32>(CA);
        bsortU<32>(CB);
        // half-cleaner: lower 32 of bitonic concat(CA, rev(CB)) — min only
#pragma unroll
        for (int i = 0; i < 32; ++i) {
            u64 a = CA[i], b = CB[31 - i];
            K[i] = a < b ? a : b;
        }
        // bitonic merge of the (bitonic) lower half -> ascending
#pragma unroll
        for (int j = 16; j > 0; j >>= 1) {
#pragma unroll
            for (int x = 0; x < 32; ++x) {
                if ((x & j) == 0) {
                    int l = x | j;
                    u64 va = K[x], vb = K[l];
                    bool sw = va > vb;
                    K[x] = sw ? vb : va;
                    K[l] = sw ? va : vb;
                }
            }
        }
    }

    // ---- epilogue: ids, validity, sort, dedup, sort, write ----
    float Sout[32];
    int e[32];
#pragma unroll
    for (int n = 0; n < 32; ++n) {
        u64 k = K[n];
        float S = __uint_as_float((uint)(k >> 24));
        Sout[n] = S;
        int id = (int)(((uint)k & 0x3FFFFu) >> 1);
        bool valid = (S < 5e29f) && (id < VOCAB);
        e[n] = valid ? id : SENTV;
    }
    bsort32i(e);
    int f[32];
    f[0] = e[0];
#pragma unroll
    for (int n = 1; n < 32; ++n) f[n] = (e[n] == e[n - 1]) ? SENTV : e[n];
    bsort32i(f);

    float* out_ids = out + (size_t)tok * 32;
    float* out_sc  = out + (size_t)T * 32 + (size_t)tok * 32;
#pragma unroll
    for (int g = 0; g < 8; ++g) {
        float4 vi;
        vi.x = (f[4 * g + 0] == SENTV) ? -1.0f : (float)f[4 * g + 0];
        vi.y = (f[4 * g + 1] == SENTV) ? -1.0f : (float)f[4 * g + 1];
        vi.z = (f[4 * g + 2] == SENTV) ? -1.0f : (float)f[4 * g + 2];
        vi.w = (f[4 * g + 3] == SENTV) ? -1.0f : (float)f[4 * g + 3];
        *(float4*)(out_ids + 4 * g) = vi;
        float4 vs = make_float4(Sout[4 * g], Sout[4 * g + 1],
                                Sout[4 * g + 2], Sout[4 * g + 3]);
        *(float4*)(out_sc + 4 * g) = vs;
    }
}

extern "C" void kernel_launch(void* const* d_in, const int* in_sizes, int n_in,
                              void* d_out, int out_size, void* d_ws, size_t ws_size,
                              hipStream_t stream) {
    const float* y = (const float*)d_in[0];
    const float* h = (const float*)d_in[1];
    const int T = in_sizes[0] / 18;               // 131072
    const int grid = (T + BLK - 1) / BLK;         // 512 blocks of 256
    beam_kernel<<<grid, BLK, 0, stream>>>(y, h, (float*)d_out, T);
}

// Round 6
// 111.712 us; speedup vs baseline: 1.8727x; 1.3999x over previous
//
#include <hip/hip_runtime.h>
#include <stdint.h>

typedef unsigned int uint;
typedef unsigned long long u64;

#define BLK   256
#define VOCAB 128000
#define SENTV (1 << 30)

// Ascending compare-exchange on u64.
__device__ __forceinline__ void ce(u64 &a, u64 &b) {
    u64 x = a, yv = b;
    bool sw = x > yv;
    a = sw ? yv : x;
    b = sw ? x : yv;
}

// Full bitonic sort (assumption-free) — used only for tiny early phases.
template<int N>
__device__ __forceinline__ void bsortU(u64 (&a)[N]) {
#pragma unroll
    for (int k = 2; k <= N; k <<= 1) {
#pragma unroll
        for (int j = k >> 1; j > 0; j >>= 1) {
#pragma unroll
            for (int x = 0; x < N; ++x) {
                int l = x ^ j;
                if (l > x) {
                    u64 va = a[x], vb = a[l];
                    bool sw = va > vb;
                    u64 mn = sw ? vb : va, mx = sw ? va : vb;
                    bool up = (x & k) == 0;
                    a[x] = up ? mn : mx;
                    a[l] = up ? mx : mn;
                }
            }
        }
    }
}

// One odd-even transposition pass pair: exactly sorts a sequence that is
// ascending except for descending runs of length <= 2 (the equal-sum tie runs).
template<int N>
__device__ __forceinline__ void oefix(u64 (&a)[N]) {
#pragma unroll
    for (int i = 0; i + 1 < N; i += 2) ce(a[i], a[i + 1]);
#pragma unroll
    for (int i = 1; i + 1 < N; i += 2) ce(a[i], a[i + 1]);
}

// Bitonic merge: sorts any bitonic sequence ascending.
template<int N>
__device__ __forceinline__ void bmerge(u64 (&a)[N]) {
#pragma unroll
    for (int j = N >> 1; j > 0; j >>= 1) {
#pragma unroll
        for (int x = 0; x < N; ++x) {
            if ((x & j) == 0) ce(a[x], a[x | j]);
        }
    }
}

// Build interleaved candidates (tiny phases, full-sorted afterwards).
// key = [score:31]<<24 | (63-flat)<<18 | path18 ; anti-stable ties via 63-flat.
template<int R>
__device__ __forceinline__ void build_il(const u64 (&K)[32], float cd0, float cd1,
                                         uint s0c, uint s1c, u64 (&C)[2 * R]) {
#pragma clang fp contract(off)
#pragma unroll
    for (int n = 0; n < R; ++n) {
        u64 base = K[n];
        float Sp = __uint_as_float((uint)(base >> 24));
        uint pp = ((uint)base & 0x3FFFFu) << 2;
        float v0 = Sp + cd0, v1 = Sp + cd1;
        C[2 * n]     = ((u64)__float_as_uint(v0) << 24) | ((u64)(uint)(63 - 2 * n) << 18) | (pp | s0c);
        C[2 * n + 1] = ((u64)__float_as_uint(v1) << 24) | ((u64)(uint)(62 - 2 * n) << 18) | (pp | s1c);
    }
}

// Build the two per-child candidate lists separately (merge path).
template<int R>
__device__ __forceinline__ void build2(const u64 (&K)[32], float cd0, float cd1,
                                       uint s0c, uint s1c, u64 (&A)[R], u64 (&B)[R]) {
#pragma clang fp contract(off)
#pragma unroll
    for (int n = 0; n < R; ++n) {
        u64 base = K[n];
        float Sp = __uint_as_float((uint)(base >> 24));
        uint pp = ((uint)base & 0x3FFFFu) << 2;
        float v0 = Sp + cd0, v1 = Sp + cd1;
        A[n] = ((u64)__float_as_uint(v0) << 24) | ((u64)(uint)(63 - 2 * n) << 18) | (pp | s0c);
        B[n] = ((u64)__float_as_uint(v1) << 24) | ((u64)(uint)(62 - 2 * n) << 18) | (pp | s1c);
    }
}

// Bitonic sort 32 ints ascending via v_min_i32/v_max_i32 (2 VALU per CE).
__device__ __forceinline__ void bsort32i(int (&a)[32]) {
#pragma unroll
    for (int k = 2; k <= 32; k <<= 1) {
#pragma unroll
        for (int j = k >> 1; j > 0; j >>= 1) {
#pragma unroll
            for (int x = 0; x < 32; ++x) {
                int l = x ^ j;
                if (l > x) {
                    int va = a[x], vb = a[l];
                    int mn = min(va, vb), mx = max(va, vb);
                    bool up = (x & k) == 0;
                    a[x] = up ? mn : mx;
                    a[l] = up ? mx : mn;
                }
            }
        }
    }
}

__global__ __launch_bounds__(BLK, 2)
void beam_kernel(const float* __restrict__ y, const float* __restrict__ h,
                 float* __restrict__ out, int T)
{
#pragma clang fp contract(off)
    const int tok = blockIdx.x * BLK + threadIdx.x;
    if (tok >= T) return;

    // ---- ZF equalize + per-position top-2-of-4 QPSK distances (strict fp32) ----
    const float hr = h[2 * tok], hi = h[2 * tok + 1];
    const float den = hr * hr + hi * hi;

    float d0r[9], d1r[9];
    uint64_t sympack = 0;                          // 4 bits per step: s0 | s1<<2
    const float C = 0.70710678118654752440f;       // fp32 0x3F3504F3 == np constellation
#pragma unroll
    for (int l = 0; l < 9; ++l) {
        float yr = y[tok * 18 + l];
        float yi = y[tok * 18 + 9 + l];
        float nr = yr * hr + yi * hi;
        float ni = yi * hr - yr * hi;
        float rr = nr / den;
        float ri = ni / den;
        float em = rr - C, ep = rr + C;
        float fm = ri - C, fq = ri + C;
        float aa = em * em, bb = ep * ep, pq = fm * fm, qq = fq * fq;
        float q0 = aa + pq, q1 = bb + pq, q2 = aa + qq, q3 = bb + qq;
        float m0 = q0; int s0 = 0;
        if (q1 < m0) { m0 = q1; s0 = 1; }
        if (q2 < m0) { m0 = q2; s0 = 2; }
        if (q3 < m0) { m0 = q3; s0 = 3; }
        float m1 = __builtin_inff(); int s1 = 0;
        if (s0 != 0 && q0 < m1) { m1 = q0; s1 = 0; }
        if (s0 != 1 && q1 < m1) { m1 = q1; s1 = 1; }
        if (s0 != 2 && q2 < m1) { m1 = q2; s1 = 2; }
        if (s0 != 3 && q3 < m1) { m1 = q3; s1 = 3; }
        d0r[l] = m0; d1r[l] = m1;
        sympack |= (uint64_t)(uint)(s0 | (s1 << 2)) << (4 * l);
    }

    // ---- beam state: real beams only, always kept fully key-sorted ascending ----
    u64 K[32];
#pragma unroll
    for (int n = 0; n < 32; ++n) K[n] = 0;

#define NIB(t) ((uint)(sympack >> (4 * (t))))
    // t=0..2: tiny — interleaved build + full sort (2,4,8 candidates)
    { u64 Cc[2]; build_il<1>(K, d0r[0], d1r[0], NIB(0) & 3u, (NIB(0) >> 2) & 3u, Cc);
      bsortU<2>(Cc);
#pragma unroll
      for (int n = 0; n < 2; ++n) K[n] = Cc[n]; }
    { u64 Cc[4]; build_il<2>(K, d0r[1], d1r[1], NIB(1) & 3u, (NIB(1) >> 2) & 3u, Cc);
      bsortU<4>(Cc);
#pragma unroll
      for (int n = 0; n < 4; ++n) K[n] = Cc[n]; }
    { u64 Cc[8]; build_il<4>(K, d0r[2], d1r[2], NIB(2) & 3u, (NIB(2) >> 2) & 3u, Cc);
      bsortU<8>(Cc);
#pragma unroll
      for (int n = 0; n < 8; ++n) K[n] = Cc[n]; }

    // t=3: 16 candidates, all survive — tie-fix + bitonic merge of two sorted 8-lists
    { u64 A[8], B[8];
      build2<8>(K, d0r[3], d1r[3], NIB(3) & 3u, (NIB(3) >> 2) & 3u, A, B);
      oefix<8>(A); oefix<8>(B);
      u64 M[16];
#pragma unroll
      for (int i = 0; i < 8; ++i) { M[i] = A[i]; M[15 - i] = B[i]; }
      bmerge<16>(M);
#pragma unroll
      for (int i = 0; i < 16; ++i) K[i] = M[i]; }

    // t=4: 32 candidates, all survive
    { u64 A[16], B[16];
      build2<16>(K, d0r[4], d1r[4], NIB(4) & 3u, (NIB(4) >> 2) & 3u, A, B);
      oefix<16>(A); oefix<16>(B);
      u64 M[32];
#pragma unroll
      for (int i = 0; i < 16; ++i) { M[i] = A[i]; M[31 - i] = B[i]; }
      bmerge<32>(M);
#pragma unroll
      for (int i = 0; i < 32; ++i) K[i] = M[i]; }
#undef NIB

    // t=5..8: 64 candidates -> sorted lowest 32.
    // Lists are ascending except <=2-long equal-sum tie runs (fp add is
    // monotone over the sorted K); oefix makes them fully sorted, then
    // half-cleaner + bitonic merge is an exact comparison network.
    float e0[4] = { d0r[5], d0r[6], d0r[7], d0r[8] };
    float e1[4] = { d1r[5], d1r[6], d1r[7], d1r[8] };
    uint sp = (uint)(sympack >> 20);
#pragma unroll 1
    for (int t = 0; t < 4; ++t) {
        const float cd0 = e0[0], cd1 = e1[0];
#pragma unroll
        for (int k = 0; k < 3; ++k) { e0[k] = e0[k + 1]; e1[k] = e1[k + 1]; }
        const uint nib = sp & 15u; sp >>= 4;

        u64 CA[32], CB[32];
        build2<32>(K, cd0, cd1, nib & 3u, (nib >> 2) & 3u, CA, CB);
        oefix<32>(CA); oefix<32>(CB);
        // half-cleaner: lowest 32 of bitonic concat(CA, rev(CB)) — min only
#pragma unroll
        for (int i = 0; i < 32; ++i) {
            u64 a = CA[i], b = CB[31 - i];
            K[i] = a < b ? a : b;
        }
        bmerge<32>(K);                             // bitonic lower half -> sorted
    }

    // ---- epilogue: ids, validity, sort, dedup, sort, write ----
    float Sout[32];
    int e[32];
#pragma unroll
    for (int n = 0; n < 32; ++n) {
        u64 k = K[n];
        float S = __uint_as_float((uint)(k >> 24));
        Sout[n] = S;
        int id = (int)(((uint)k & 0x3FFFFu) >> 1);
        bool valid = (S < 5e29f) && (id < VOCAB);
        e[n] = valid ? id : SENTV;
    }
    bsort32i(e);
    int f[32];
    f[0] = e[0];
#pragma unroll
    for (int n = 1; n < 32; ++n) f[n] = (e[n] == e[n - 1]) ? SENTV : e[n];
    bsort32i(f);

    float* out_ids = out + (size_t)tok * 32;
    float* out_sc  = out + (size_t)T * 32 + (size_t)tok * 32;
#pragma unroll
    for (int g = 0; g < 8; ++g) {
        float4 vi;
        vi.x = (f[4 * g + 0] == SENTV) ? -1.0f : (float)f[4 * g + 0];
        vi.y = (f[4 * g + 1] == SENTV) ? -1.0f : (float)f[4 * g + 1];
        vi.z = (f[4 * g + 2] == SENTV) ? -1.0f : (float)f[4 * g + 2];
        vi.w = (f[4 * g + 3] == SENTV) ? -1.0f : (float)f[4 * g + 3];
        *(float4*)(out_ids + 4 * g) = vi;
        float4 vs = make_float4(Sout[4 * g], Sout[4 * g + 1],
                                Sout[4 * g + 2], Sout[4 * g + 3]);
        *(float4*)(out_sc + 4 * g) = vs;
    }
}

extern "C" void kernel_launch(void* const* d_in, const int* in_sizes, int n_in,
                              void* d_out, int out_size, void* d_ws, size_t ws_size,
                              hipStream_t stream) {
    const float* y = (const float*)d_in[0];
    const float* h = (const float*)d_in[1];
    const int T = in_sizes[0] / 18;               // 131072
    const int grid = (T + BLK - 1) / BLK;         // 512 blocks of 256
    beam_kernel<<<grid, BLK, 0, stream>>>(y, h, (float*)d_out, T);
}

// Round 7
// 100.101 us; speedup vs baseline: 2.0899x; 1.1160x over previous
//
#include <hip/hip_runtime.h>
#include <stdint.h>

typedef unsigned int uint;
typedef unsigned long long u64;

#define BLK   256
#define VOCAB 128000
#define SENTV (1 << 30)

// Ascending compare-exchange on 55-bit keys via f64 min/max.
// Keys have bits 62:55 == 0 -> always tiny positive finite doubles (exp<=7,
// never NaN/Inf); IEEE non-negative doubles order == unsigned bit order
// (denormals included; f64 denorms are always IEEE on AMD). 2 VALU, no vcc.
__device__ __forceinline__ void ce(u64 &a, u64 &b) {
    double x = __longlong_as_double(a), y = __longlong_as_double(b);
    double mn = __builtin_fmin(x, y), mx = __builtin_fmax(x, y);
    a = __double_as_longlong(mn);
    b = __double_as_longlong(mx);
}

__device__ __forceinline__ u64 kmin(u64 a, u64 b) {
    return __double_as_longlong(__builtin_fmin(__longlong_as_double(a),
                                               __longlong_as_double(b)));
}

// Full bitonic sort (assumption-free) — tiny early phases only.
template<int N>
__device__ __forceinline__ void bsortU(u64 (&a)[N]) {
#pragma unroll
    for (int k = 2; k <= N; k <<= 1) {
#pragma unroll
        for (int j = k >> 1; j > 0; j >>= 1) {
#pragma unroll
            for (int x = 0; x < N; ++x) {
                int l = x ^ j;
                if (l > x) {
                    if ((x & k) == 0) ce(a[x], a[l]);
                    else              ce(a[l], a[x]);
                }
            }
        }
    }
}

// One odd-even transposition pass pair: exactly sorts a sequence that is
// ascending except for descending runs of length <= 2 (equal-sum tie runs).
template<int N>
__device__ __forceinline__ void oefix(u64 (&a)[N]) {
#pragma unroll
    for (int i = 0; i + 1 < N; i += 2) ce(a[i], a[i + 1]);
#pragma unroll
    for (int i = 1; i + 1 < N; i += 2) ce(a[i], a[i + 1]);
}

// Bitonic merge: sorts any bitonic sequence ascending.
template<int N>
__device__ __forceinline__ void bmerge(u64 (&a)[N]) {
#pragma unroll
    for (int j = N >> 1; j > 0; j >>= 1) {
#pragma unroll
        for (int x = 0; x < N; ++x) {
            if ((x & j) == 0) ce(a[x], a[x | j]);
        }
    }
}

// key = [score:31]<<24 | (63-flat)<<18 | path18 ; anti-stable ties via 63-flat.
template<int R>
__device__ __forceinline__ void build_il(const u64 (&K)[32], float cd0, float cd1,
                                         uint s0c, uint s1c, u64 (&C)[2 * R]) {
#pragma clang fp contract(off)
    const uint xm = (1u << 18) | (s0c ^ s1c);
#pragma unroll
    for (int n = 0; n < R; ++n) {
        u64 base = K[n];
        float Sp = __uint_as_float((uint)(base >> 24));
        uint c0 = ((((uint)base & 0x3FFFFu) << 2) | s0c) | ((uint)(63 - 2 * n) << 18);
        uint c1 = c0 ^ xm;
        float v0 = Sp + cd0, v1 = Sp + cd1;
        C[2 * n]     = ((u64)__float_as_uint(v0) << 24) | c0;
        C[2 * n + 1] = ((u64)__float_as_uint(v1) << 24) | c1;
    }
}

// Build the two per-child candidate lists separately (merge path).
template<int R>
__device__ __forceinline__ void build2(const u64 (&K)[32], float cd0, float cd1,
                                       uint s0c, uint s1c, u64 (&A)[R], u64 (&B)[R]) {
#pragma clang fp contract(off)
    const uint xm = (1u << 18) | (s0c ^ s1c);
#pragma unroll
    for (int n = 0; n < R; ++n) {
        u64 base = K[n];
        float Sp = __uint_as_float((uint)(base >> 24));
        uint c0 = ((((uint)base & 0x3FFFFu) << 2) | s0c) | ((uint)(63 - 2 * n) << 18);
        uint c1 = c0 ^ xm;
        float v0 = Sp + cd0, v1 = Sp + cd1;
        A[n] = ((u64)__float_as_uint(v0) << 24) | c0;
        B[n] = ((u64)__float_as_uint(v1) << 24) | c1;
    }
}

// Bitonic sort 32 ints ascending via v_min_i32/v_max_i32 (2 VALU per CE).
__device__ __forceinline__ void bsort32i(int (&a)[32]) {
#pragma unroll
    for (int k = 2; k <= 32; k <<= 1) {
#pragma unroll
        for (int j = k >> 1; j > 0; j >>= 1) {
#pragma unroll
            for (int x = 0; x < 32; ++x) {
                int l = x ^ j;
                if (l > x) {
                    int va = a[x], vb = a[l];
                    int mn = min(va, vb), mx = max(va, vb);
                    bool up = (x & k) == 0;
                    a[x] = up ? mn : mx;
                    a[l] = up ? mx : mn;
                }
            }
        }
    }
}

__global__ __launch_bounds__(BLK, 2)
void beam_kernel(const float* __restrict__ y, const float* __restrict__ h,
                 float* __restrict__ out, int T)
{
#pragma clang fp contract(off)
    const int tok = blockIdx.x * BLK + threadIdx.x;
    if (tok >= T) return;

    // ---- ZF equalize + per-position top-2-of-4 QPSK distances (strict fp32) ----
    const float hr = h[2 * tok], hi = h[2 * tok + 1];
    const float den = hr * hr + hi * hi;

    float d0r[9], d1r[9];
    uint64_t sympack = 0;                          // 4 bits per step: s0 | s1<<2
    const float C = 0.70710678118654752440f;       // fp32 0x3F3504F3 == np constellation
#pragma unroll
    for (int l = 0; l < 9; ++l) {
        float yr = y[tok * 18 + l];
        float yi = y[tok * 18 + 9 + l];
        float nr = yr * hr + yi * hi;
        float ni = yi * hr - yr * hi;
        float rr = nr / den;
        float ri = ni / den;
        float em = rr - C, ep = rr + C;
        float fm = ri - C, fq = ri + C;
        float aa = em * em, bb = ep * ep, pq = fm * fm, qq = fq * fq;
        float q0 = aa + pq, q1 = bb + pq, q2 = aa + qq, q3 = bb + qq;
        float m0 = q0; int s0 = 0;
        if (q1 < m0) { m0 = q1; s0 = 1; }
        if (q2 < m0) { m0 = q2; s0 = 2; }
        if (q3 < m0) { m0 = q3; s0 = 3; }
        float m1 = __builtin_inff(); int s1 = 0;
        if (s0 != 0 && q0 < m1) { m1 = q0; s1 = 0; }
        if (s0 != 1 && q1 < m1) { m1 = q1; s1 = 1; }
        if (s0 != 2 && q2 < m1) { m1 = q2; s1 = 2; }
        if (s0 != 3 && q3 < m1) { m1 = q3; s1 = 3; }
        d0r[l] = m0; d1r[l] = m1;
        sympack |= (uint64_t)(uint)(s0 | (s1 << 2)) << (4 * l);
    }

    // ---- beam state: real beams only, always fully key-sorted ascending ----
    u64 K[32];
#pragma unroll
    for (int n = 0; n < 32; ++n) K[n] = 0;

#define NIB(t) ((uint)(sympack >> (4 * (t))))
    // t=0..2: tiny — interleaved build + full sort (2,4,8 candidates)
    { u64 Cc[2]; build_il<1>(K, d0r[0], d1r[0], NIB(0) & 3u, (NIB(0) >> 2) & 3u, Cc);
      bsortU<2>(Cc);
#pragma unroll
      for (int n = 0; n < 2; ++n) K[n] = Cc[n]; }
    { u64 Cc[4]; build_il<2>(K, d0r[1], d1r[1], NIB(1) & 3u, (NIB(1) >> 2) & 3u, Cc);
      bsortU<4>(Cc);
#pragma unroll
      for (int n = 0; n < 4; ++n) K[n] = Cc[n]; }
    { u64 Cc[8]; build_il<4>(K, d0r[2], d1r[2], NIB(2) & 3u, (NIB(2) >> 2) & 3u, Cc);
      bsortU<8>(Cc);
#pragma unroll
      for (int n = 0; n < 8; ++n) K[n] = Cc[n]; }

    // t=3: 16 candidates, all survive — tie-fix + bitonic merge of sorted 8-lists
    { u64 A[8], B[8];
      build2<8>(K, d0r[3], d1r[3], NIB(3) & 3u, (NIB(3) >> 2) & 3u, A, B);
      oefix<8>(A); oefix<8>(B);
      u64 M[16];
#pragma unroll
      for (int i = 0; i < 8; ++i) { M[i] = A[i]; M[15 - i] = B[i]; }
      bmerge<16>(M);
#pragma unroll
      for (int i = 0; i < 16; ++i) K[i] = M[i]; }

    // t=4: 32 candidates, all survive
    { u64 A[16], B[16];
      build2<16>(K, d0r[4], d1r[4], NIB(4) & 3u, (NIB(4) >> 2) & 3u, A, B);
      oefix<16>(A); oefix<16>(B);
      u64 M[32];
#pragma unroll
      for (int i = 0; i < 16; ++i) { M[i] = A[i]; M[31 - i] = B[i]; }
      bmerge<32>(M);
#pragma unroll
      for (int i = 0; i < 32; ++i) K[i] = M[i]; }
#undef NIB

    // t=5..8: 64 candidates -> sorted lowest 32.
    // Lists are ascending except <=2-long equal-sum tie runs (fp add is
    // monotone over the sorted K); oefix sorts them fully, then
    // half-cleaner + bitonic merge is an exact comparison network.
    float e0[4] = { d0r[5], d0r[6], d0r[7], d0r[8] };
    float e1[4] = { d1r[5], d1r[6], d1r[7], d1r[8] };
    uint sp = (uint)(sympack >> 20);
#pragma unroll 1
    for (int t = 0; t < 4; ++t) {
        const float cd0 = e0[0], cd1 = e1[0];
#pragma unroll
        for (int k = 0; k < 3; ++k) { e0[k] = e0[k + 1]; e1[k] = e1[k + 1]; }
        const uint nib = sp & 15u; sp >>= 4;

        u64 CA[32], CB[32];
        build2<32>(K, cd0, cd1, nib & 3u, (nib >> 2) & 3u, CA, CB);
        oefix<32>(CA); oefix<32>(CB);
        // half-cleaner: lowest 32 of bitonic concat(CA, rev(CB)) — min only
#pragma unroll
        for (int i = 0; i < 32; ++i) K[i] = kmin(CA[i], CB[31 - i]);
        bmerge<32>(K);                             // bitonic lower half -> sorted
    }

    // ---- epilogue: ids, validity, sort, dedup, sort, write ----
    float Sout[32];
    int e[32];
#pragma unroll
    for (int n = 0; n < 32; ++n) {
        u64 k = K[n];
        float S = __uint_as_float((uint)(k >> 24));
        Sout[n] = S;
        int id = (int)(((uint)k & 0x3FFFFu) >> 1);
        bool valid = (S < 5e29f) && (id < VOCAB);
        e[n] = valid ? id : SENTV;
    }
    bsort32i(e);
    int f[32];
    f[0] = e[0];
#pragma unroll
    for (int n = 1; n < 32; ++n) f[n] = (e[n] == e[n - 1]) ? SENTV : e[n];
    bsort32i(f);

    float* out_ids = out + (size_t)tok * 32;
    float* out_sc  = out + (size_t)T * 32 + (size_t)tok * 32;
#pragma unroll
    for (int g = 0; g < 8; ++g) {
        float4 vi;
        vi.x = (f[4 * g + 0] == SENTV) ? -1.0f : (float)f[4 * g + 0];
        vi.y = (f[4 * g + 1] == SENTV) ? -1.0f : (float)f[4 * g + 1];
        vi.z = (f[4 * g + 2] == SENTV) ? -1.0f : (float)f[4 * g + 2];
        vi.w = (f[4 * g + 3] == SENTV) ? -1.0f : (float)f[4 * g + 3];
        *(float4*)(out_ids + 4 * g) = vi;
        float4 vs = make_float4(Sout[4 * g], Sout[4 * g + 1],
                                Sout[4 * g + 2], Sout[4 * g + 3]);
        *(float4*)(out_sc + 4 * g) = vs;
    }
}

extern "C" void kernel_launch(void* const* d_in, const int* in_sizes, int n_in,
                              void* d_out, int out_size, void* d_ws, size_t ws_size,
                              hipStream_t stream) {
    const float* y = (const float*)d_in[0];
    const float* h = (const float*)d_in[1];
    const int T = in_sizes[0] / 18;               // 131072
    const int grid = (T + BLK - 1) / BLK;         // 512 blocks of 256
    beam_kernel<<<grid, BLK, 0, stream>>>(y, h, (float*)d_out, T);
}